// Round 1
// baseline (638.188 us; speedup 1.0000x reference)
//
#include <hip/hip_runtime.h>
#include <hip/hip_bf16.h>

#define B_ 4
#define S_ 2048
#define HID_ 2048
#define NH_ 8
#define HD_ 256
#define QKVN 2560

typedef unsigned short u16;
typedef __attribute__((ext_vector_type(4))) float f32x4;
typedef __attribute__((ext_vector_type(8))) short bf16x8;

__device__ __forceinline__ float bf2f(u16 u) {
  union { unsigned int i; float f; } v; v.i = ((unsigned int)u) << 16; return v.f;
}
__device__ __forceinline__ u16 f2bf(float f) {
  union { unsigned int i; float f; } v; v.f = f;
  unsigned int r = v.i + 0x7fffu + ((v.i >> 16) & 1u);
  return (u16)(r >> 16);
}

// ---------------- cast x (f32 -> bf16), 8 elems/thread ----------------
__global__ void cast_f32_bf16(const float* __restrict__ in, u16* __restrict__ out, int n8) {
  int i = blockIdx.x * blockDim.x + threadIdx.x;
  int stride = gridDim.x * blockDim.x;
  for (; i < n8; i += stride) {
    const float4* p = (const float4*)(in + (size_t)i * 8);
    float4 a = p[0], b = p[1];
    u16 o[8] = {f2bf(a.x), f2bf(a.y), f2bf(a.z), f2bf(a.w),
                f2bf(b.x), f2bf(b.y), f2bf(b.z), f2bf(b.w)};
    *(uint4*)(out + (size_t)i * 8) = *(const uint4*)o;
  }
}

// ------------- transpose + cast: in[R][C] f32 -> out[C][R] bf16 -------------
__global__ void transpose_cast(const float* __restrict__ in, u16* __restrict__ out, int R, int C) {
  __shared__ float t[32][33];
  int c0 = blockIdx.x * 32, r0 = blockIdx.y * 32;
  int tx = threadIdx.x, ty = threadIdx.y;
#pragma unroll
  for (int i = 0; i < 4; ++i)
    t[ty + i * 8][tx] = in[(size_t)(r0 + ty + i * 8) * C + c0 + tx];
  __syncthreads();
#pragma unroll
  for (int i = 0; i < 4; ++i)
    out[(size_t)(c0 + ty + i * 8) * R + r0 + tx] = f2bf(t[tx][ty + i * 8]);
}

// ------------- transpose bf16 (per-batch): in[R][C] -> out[C][R] -------------
__global__ void transpose_bf16(const u16* __restrict__ in, u16* __restrict__ out, int R, int C) {
  __shared__ u16 t[32][33];
  in += (size_t)blockIdx.z * R * C;
  out += (size_t)blockIdx.z * R * C;
  int c0 = blockIdx.x * 32, r0 = blockIdx.y * 32;
  int tx = threadIdx.x, ty = threadIdx.y;
#pragma unroll
  for (int i = 0; i < 4; ++i)
    t[ty + i * 8][tx] = in[(size_t)(r0 + ty + i * 8) * C + c0 + tx];
  __syncthreads();
#pragma unroll
  for (int i = 0; i < 4; ++i)
    out[(size_t)(c0 + ty + i * 8) * R + r0 + tx] = t[tx][ty + i * 8];
}

// ---------------- m97-style bf16 GEMM: C[M][N] = A[M][K] * BT[N][K]^T + bias ----------------
template <bool OUT_F32>
__global__ __launch_bounds__(256) void gemm_bt(const u16* __restrict__ A, const u16* __restrict__ BT,
                                               const float* __restrict__ bias, void* __restrict__ Cout,
                                               int M, int N, int K) {
  __shared__ u16 As[128 * 32];
  __shared__ u16 Bs[128 * 32];
  int nwg = gridDim.x;
  int bid = (int)blockIdx.x;
  bid = (bid & 7) * (nwg >> 3) + (bid >> 3);  // XCD swizzle (nwg % 8 == 0)
  int ntiles = N >> 7;
  int m0 = (bid / ntiles) << 7, n0 = (bid % ntiles) << 7;
  int tid = threadIdx.x, w = tid >> 6, lane = tid & 63;
  int wr = w >> 1, wc = w & 1;
  int l15 = lane & 15, lg = lane >> 4;
  f32x4 acc[4][4] = {};
  int crow = lane >> 2;          // row within 16-row chunk
  int ccol = (lane & 3) * 8;     // elem offset within 32-wide k slab
  for (int k0 = 0; k0 < K; k0 += 32) {
#pragma unroll
    for (int i = 0; i < 2; ++i) {
      int c = w * 2 + i;
      const u16* ga = A + (size_t)(m0 + c * 16 + crow) * K + k0 + ccol;
      const u16* gb = BT + (size_t)(n0 + c * 16 + crow) * K + k0 + ccol;
      __builtin_amdgcn_global_load_lds((const __attribute__((address_space(1))) void*)ga,
                                       (__attribute__((address_space(3))) void*)(As + c * 512), 16, 0, 0);
      __builtin_amdgcn_global_load_lds((const __attribute__((address_space(1))) void*)gb,
                                       (__attribute__((address_space(3))) void*)(Bs + c * 512), 16, 0, 0);
    }
    __syncthreads();
    bf16x8 af[4], bfr[4];
#pragma unroll
    for (int r = 0; r < 4; ++r)
      af[r] = *(const bf16x8*)&As[(wr * 64 + r * 16 + l15) * 32 + lg * 8];
#pragma unroll
    for (int c = 0; c < 4; ++c)
      bfr[c] = *(const bf16x8*)&Bs[(wc * 64 + c * 16 + l15) * 32 + lg * 8];
#pragma unroll
    for (int r = 0; r < 4; ++r)
#pragma unroll
      for (int c = 0; c < 4; ++c)
        acc[r][c] = __builtin_amdgcn_mfma_f32_16x16x32_bf16(af[r], bfr[c], acc[r][c], 0, 0, 0);
    __syncthreads();
  }
#pragma unroll
  for (int r = 0; r < 4; ++r) {
    int mrow = m0 + wr * 64 + r * 16 + lg * 4;
#pragma unroll
    for (int c = 0; c < 4; ++c) {
      int col = n0 + wc * 64 + c * 16 + l15;
      float bv = bias[col];
#pragma unroll
      for (int j = 0; j < 4; ++j) {
        float v = acc[r][c][j] + bv;
        if (OUT_F32)
          ((float*)Cout)[(size_t)(mrow + j) * N + col] = v;
        else
          ((u16*)Cout)[(size_t)(mrow + j) * N + col] = f2bf(v);
      }
    }
  }
}

// ---------------- RoPE + scatter qkv -> q_all / k / v ----------------
__global__ void rope_scatter(const u16* __restrict__ qkv, const float* __restrict__ freqs,
                             u16* __restrict__ qo, u16* __restrict__ ko, u16* __restrict__ vo) {
  const int per_row = QKVN / 8;  // 320
  const int total = B_ * S_ * per_row;
  int i = blockIdx.x * blockDim.x + threadIdx.x;
  int stride = gridDim.x * blockDim.x;
  for (; i < total; i += stride) {
    int m = i / per_row;
    int n8 = (i - m * per_row) * 8;
    int b = m >> 11, s = m & 2047;
    uint4 raw = *(const uint4*)(qkv + (size_t)m * QKVN + n8);
    const u16* u = (const u16*)&raw;
    if (n8 < 2304) {
      int d = (n8 < 2048) ? (n8 & 255) : (n8 - 2048);
      float scl = (n8 < 2048) ? 0.0625f : 1.0f;  // fold HD^-0.5 into q
      const float* fp = freqs + ((size_t)s * 128 + (d >> 1)) * 2;
      float4 f0 = *(const float4*)fp;
      float4 f1 = *(const float4*)(fp + 4);
      float fc[8] = {f0.x, f0.y, f0.z, f0.w, f1.x, f1.y, f1.z, f1.w};
      u16 o[8];
#pragma unroll
      for (int p = 0; p < 4; ++p) {
        float r = bf2f(u[2 * p]), im = bf2f(u[2 * p + 1]);
        float c = fc[2 * p], sn = fc[2 * p + 1];
        o[2 * p] = f2bf((r * c - im * sn) * scl);
        o[2 * p + 1] = f2bf((r * sn + im * c) * scl);
      }
      u16* dst;
      if (n8 < 2048) {
        int h = n8 >> 8;
        dst = qo + (((size_t)(b * NH_ + h) * S_ + s) << 8) + (n8 & 255);
      } else {
        dst = ko + (((size_t)(b * S_ + s)) << 8) + d;
      }
      *(uint4*)dst = *(const uint4*)o;
    } else {
      int d = n8 - 2304;
      u16* dst = vo + (((size_t)(b * S_ + s)) << 8) + d;
      *(uint4*)dst = raw;
    }
  }
}

// ---------------- flash attention (causal), QBLK=64 (4 waves x 16 rows), KBLK=64 ----------------
__global__ __launch_bounds__(256) void flash_attn(const u16* __restrict__ Q, const u16* __restrict__ Kg,
                                                  const u16* __restrict__ VT, u16* __restrict__ O) {
  __shared__ u16 Ks[64 * 256];    // 32 KB, rows 512B, XOR-swizzled
  __shared__ u16 Vs[256 * 64];    // 32 KB (V^T), rows 128B, XOR-swizzled
  __shared__ u16 Ps[4 * 16 * 64]; // 8 KB, per-wave P tiles, swizzled
  int qt = 31 - ((int)blockIdx.x & 31);
  int bh = (int)blockIdx.x >> 5;
  int b = bh >> 3, h = bh & 7;
  int tid = threadIdx.x, w = tid >> 6, lane = tid & 63;
  int l15 = lane & 15, lg = lane >> 4;
  int q0 = qt << 6;

  bf16x8 qf[8];
  const u16* qb = Q + ((size_t)bh * S_ + q0 + w * 16 + l15) * HD_ + lg * 8;
#pragma unroll
  for (int kc = 0; kc < 8; ++kc) qf[kc] = *(const bf16x8*)(qb + kc * 32);

  float m_r[4], l_r[4];
#pragma unroll
  for (int r = 0; r < 4; ++r) { m_r[r] = -3.0e38f; l_r[r] = 0.f; }
  f32x4 oacc[16] = {};
  const char* KsB = (const char*)Ks;
  const char* VsB = (const char*)Vs;

  for (int kt = 0; kt <= qt; ++kt) {
    __syncthreads();
    {  // stage K tile [64][256]
      const u16* kgb = Kg + ((size_t)(b * S_ + kt * 64)) * HD_;
#pragma unroll
      for (int p = 0; p < 8; ++p) {
        int idx = p * 256 + tid;
        int row = idx >> 5, c16 = idx & 31;
        uint4 val = *(const uint4*)(kgb + row * HD_ + c16 * 8);
        *(uint4*)((char*)Ks + row * 512 + ((c16 * 16) ^ ((row & 7) << 4))) = val;
      }
      // stage V^T tile [256][64]
      const u16* vgb = VT + ((size_t)b * HD_) * S_ + kt * 64;
#pragma unroll
      for (int p = 0; p < 8; ++p) {
        int idx = p * 256 + tid;
        int d = idx >> 3, c16 = idx & 7;
        uint4 val = *(const uint4*)(vgb + (size_t)d * S_ + c16 * 8);
        *(uint4*)((char*)Vs + d * 128 + ((c16 * 16) ^ ((d & 7) << 4))) = val;
      }
    }
    __syncthreads();

    // QK^T
    f32x4 sc[4] = {};
#pragma unroll
    for (int kc = 0; kc < 8; ++kc) {
#pragma unroll
      for (int ct = 0; ct < 4; ++ct) {
        int row = ct * 16 + l15;
        bf16x8 kf = *(const bf16x8*)(KsB + row * 512 + ((kc * 64 + lg * 16) ^ ((row & 7) << 4)));
        sc[ct] = __builtin_amdgcn_mfma_f32_16x16x32_bf16(qf[kc], kf, sc[ct], 0, 0, 0);
      }
    }

    // online softmax
    bool diag = (kt == qt);
#pragma unroll
    for (int r = 0; r < 4; ++r) {
      int qr = q0 + w * 16 + lg * 4 + r;
      float tmax = -3.0e38f;
#pragma unroll
      for (int ct = 0; ct < 4; ++ct) {
        float v = sc[ct][r];
        if (diag && (kt * 64 + ct * 16 + l15 > qr)) v = -3.0e38f;
        sc[ct][r] = v;
        tmax = fmaxf(tmax, v);
      }
#pragma unroll
      for (int off = 1; off < 16; off <<= 1) tmax = fmaxf(tmax, __shfl_xor(tmax, off));
      float mnew = fmaxf(m_r[r], tmax);
      float scale = __expf(m_r[r] - mnew);
      float tsum = 0.f;
#pragma unroll
      for (int ct = 0; ct < 4; ++ct) {
        float pv = __expf(sc[ct][r] - mnew);
        sc[ct][r] = pv;
        tsum += pv;
      }
#pragma unroll
      for (int off = 1; off < 16; off <<= 1) tsum += __shfl_xor(tsum, off);
      l_r[r] = l_r[r] * scale + tsum;
      m_r[r] = mnew;
#pragma unroll
      for (int dt = 0; dt < 16; ++dt) oacc[dt][r] *= scale;
    }

    // P -> per-wave LDS (swizzled), bf16
    char* pb = (char*)Ps + w * 2048;
#pragma unroll
    for (int r = 0; r < 4; ++r) {
      int prow = lg * 4 + r;
#pragma unroll
      for (int ct = 0; ct < 4; ++ct) {
        int pcol = ct * 16 + l15;
        *(u16*)(pb + prow * 128 + ((pcol * 2) ^ ((prow & 7) << 4))) = f2bf(sc[ct][r]);
      }
    }

    // PV
#pragma unroll
    for (int kc2 = 0; kc2 < 2; ++kc2) {
      int prow = l15;
      bf16x8 pf = *(const bf16x8*)((const char*)Ps + w * 2048 + prow * 128 +
                                   ((kc2 * 64 + lg * 16) ^ ((prow & 7) << 4)));
#pragma unroll
      for (int dt = 0; dt < 16; ++dt) {
        int vrow = dt * 16 + l15;
        bf16x8 vf = *(const bf16x8*)(VsB + vrow * 128 + ((kc2 * 64 + lg * 16) ^ ((vrow & 7) << 4)));
        oacc[dt] = __builtin_amdgcn_mfma_f32_16x16x32_bf16(pf, vf, oacc[dt], 0, 0, 0);
      }
    }
  }

  // epilogue: divide by l, write attout [b*S+s][h*HD+d] bf16
  float inv[4];
#pragma unroll
  for (int r = 0; r < 4; ++r) inv[r] = 1.0f / l_r[r];
  size_t obase = ((size_t)(b * S_ + q0 + w * 16 + lg * 4)) * HID_ + h * HD_ + l15;
#pragma unroll
  for (int dt = 0; dt < 16; ++dt)
#pragma unroll
    for (int j = 0; j < 4; ++j)
      O[obase + (size_t)j * HID_ + dt * 16] = f2bf(oacc[dt][j] * inv[j]);
}

extern "C" void kernel_launch(void* const* d_in, const int* in_sizes, int n_in,
                              void* d_out, int out_size, void* d_ws, size_t ws_size,
                              hipStream_t stream) {
  const float* x = (const float*)d_in[0];
  const float* w_qkv = (const float*)d_in[1];
  const float* b_qkv = (const float*)d_in[2];
  const float* w_o = (const float*)d_in[3];
  const float* b_o = (const float*)d_in[4];
  const float* freqs = (const float*)d_in[5];
  // d_in[6] is the causal mask; causality is implemented directly.

  char* ws = (char*)d_ws;
  u16* xb    = (u16*)ws;                          // 33,554,432 B
  u16* wqkvT = (u16*)(ws + 33554432);             // 10,485,760 B
  u16* woT   = (u16*)(ws + 44040192);             //  8,388,608 B
  u16* qkv   = (u16*)(ws + 52428800);             // 41,943,040 B
  u16* qall  = (u16*)(ws + 94371840);             // 33,554,432 B
  u16* kbuf  = (u16*)(ws + 127926272);            //  4,194,304 B
  u16* vbuf  = (u16*)(ws + 132120576);            //  4,194,304 B
  u16* vT    = xb;    // alias: xb dead after QKV GEMM
  u16* attout = qkv;  // alias: qkv dead after rope_scatter

  cast_f32_bf16<<<2048, 256, 0, stream>>>(x, xb, (B_ * S_ * HID_) / 8);
  transpose_cast<<<dim3(QKVN / 32, HID_ / 32), dim3(32, 8), 0, stream>>>(w_qkv, wqkvT, HID_, QKVN);
  transpose_cast<<<dim3(HID_ / 32, HID_ / 32), dim3(32, 8), 0, stream>>>(w_o, woT, HID_, HID_);
  gemm_bt<false><<<dim3(64 * 20), 256, 0, stream>>>(xb, wqkvT, b_qkv, qkv, B_ * S_, QKVN, HID_);
  rope_scatter<<<2048, 256, 0, stream>>>(qkv, freqs, qall, kbuf, vbuf);
  transpose_bf16<<<dim3(HD_ / 32, S_ / 32, B_), dim3(32, 8), 0, stream>>>(vbuf, vT, S_, HD_);
  flash_attn<<<1024, 256, 0, stream>>>(qall, kbuf, vT, attout);
  gemm_bt<true><<<dim3(64 * 16), 256, 0, stream>>>(attout, woT, b_o, d_out, B_ * S_, HID_, HID_);
}

// Round 2
// 614.635 us; speedup vs baseline: 1.0383x; 1.0383x over previous
//
#include <hip/hip_runtime.h>
#include <hip/hip_bf16.h>

#define B_ 4
#define S_ 2048
#define HID_ 2048
#define NH_ 8
#define HD_ 256
#define QKVN 2560

typedef unsigned short u16;
typedef __attribute__((ext_vector_type(4))) float f32x4;
typedef __attribute__((ext_vector_type(8))) short bf16x8;

__device__ __forceinline__ float bf2f(u16 u) {
  union { unsigned int i; float f; } v; v.i = ((unsigned int)u) << 16; return v.f;
}
__device__ __forceinline__ u16 f2bf(float f) {
  union { unsigned int i; float f; } v; v.f = f;
  unsigned int r = v.i + 0x7fffu + ((v.i >> 16) & 1u);
  return (u16)(r >> 16);
}

// ---------------- cast x (f32 -> bf16), 8 elems/thread ----------------
__global__ void cast_f32_bf16(const float* __restrict__ in, u16* __restrict__ out, int n8) {
  int i = blockIdx.x * blockDim.x + threadIdx.x;
  int stride = gridDim.x * blockDim.x;
  for (; i < n8; i += stride) {
    const float4* p = (const float4*)(in + (size_t)i * 8);
    float4 a = p[0], b = p[1];
    u16 o[8] = {f2bf(a.x), f2bf(a.y), f2bf(a.z), f2bf(a.w),
                f2bf(b.x), f2bf(b.y), f2bf(b.z), f2bf(b.w)};
    *(uint4*)(out + (size_t)i * 8) = *(const uint4*)o;
  }
}

// ------------- transpose + cast: in[R][C] f32 -> out[C][R] bf16 -------------
__global__ void transpose_cast(const float* __restrict__ in, u16* __restrict__ out, int R, int C) {
  __shared__ float t[32][33];
  int c0 = blockIdx.x * 32, r0 = blockIdx.y * 32;
  int tx = threadIdx.x, ty = threadIdx.y;
#pragma unroll
  for (int i = 0; i < 4; ++i)
    t[ty + i * 8][tx] = in[(size_t)(r0 + ty + i * 8) * C + c0 + tx];
  __syncthreads();
#pragma unroll
  for (int i = 0; i < 4; ++i)
    out[(size_t)(c0 + ty + i * 8) * R + r0 + tx] = f2bf(t[tx][ty + i * 8]);
}

// ------------- transpose bf16 (per-batch): in[R][C] -> out[C][R] -------------
__global__ void transpose_bf16(const u16* __restrict__ in, u16* __restrict__ out, int R, int C) {
  __shared__ u16 t[32][33];
  in += (size_t)blockIdx.z * R * C;
  out += (size_t)blockIdx.z * R * C;
  int c0 = blockIdx.x * 32, r0 = blockIdx.y * 32;
  int tx = threadIdx.x, ty = threadIdx.y;
#pragma unroll
  for (int i = 0; i < 4; ++i)
    t[ty + i * 8][tx] = in[(size_t)(r0 + ty + i * 8) * C + c0 + tx];
  __syncthreads();
#pragma unroll
  for (int i = 0; i < 4; ++i)
    out[(size_t)(c0 + ty + i * 8) * R + r0 + tx] = t[tx][ty + i * 8];
}

// ---------------- m97-style bf16 GEMM: C[M][N] = A[M][K] * BT[N][K]^T + bias ----------------
template <bool OUT_F32>
__global__ __launch_bounds__(256) void gemm_bt(const u16* __restrict__ A, const u16* __restrict__ BT,
                                               const float* __restrict__ bias, void* __restrict__ Cout,
                                               int M, int N, int K) {
  __shared__ u16 As[128 * 32];
  __shared__ u16 Bs[128 * 32];
  int nwg = gridDim.x;
  int bid = (int)blockIdx.x;
  bid = (bid & 7) * (nwg >> 3) + (bid >> 3);  // XCD swizzle (nwg % 8 == 0)
  int ntiles = N >> 7;
  int m0 = (bid / ntiles) << 7, n0 = (bid % ntiles) << 7;
  int tid = threadIdx.x, w = tid >> 6, lane = tid & 63;
  int wr = w >> 1, wc = w & 1;
  int l15 = lane & 15, lg = lane >> 4;
  f32x4 acc[4][4] = {};
  int crow = lane >> 2;          // row within 16-row chunk
  int ccol = (lane & 3) * 8;     // elem offset within 32-wide k slab
  for (int k0 = 0; k0 < K; k0 += 32) {
#pragma unroll
    for (int i = 0; i < 2; ++i) {
      int c = w * 2 + i;
      const u16* ga = A + (size_t)(m0 + c * 16 + crow) * K + k0 + ccol;
      const u16* gb = BT + (size_t)(n0 + c * 16 + crow) * K + k0 + ccol;
      __builtin_amdgcn_global_load_lds((const __attribute__((address_space(1))) void*)ga,
                                       (__attribute__((address_space(3))) void*)(As + c * 512), 16, 0, 0);
      __builtin_amdgcn_global_load_lds((const __attribute__((address_space(1))) void*)gb,
                                       (__attribute__((address_space(3))) void*)(Bs + c * 512), 16, 0, 0);
    }
    __syncthreads();
    bf16x8 af[4], bfr[4];
#pragma unroll
    for (int r = 0; r < 4; ++r)
      af[r] = *(const bf16x8*)&As[(wr * 64 + r * 16 + l15) * 32 + lg * 8];
#pragma unroll
    for (int c = 0; c < 4; ++c)
      bfr[c] = *(const bf16x8*)&Bs[(wc * 64 + c * 16 + l15) * 32 + lg * 8];
#pragma unroll
    for (int r = 0; r < 4; ++r)
#pragma unroll
      for (int c = 0; c < 4; ++c)
        acc[r][c] = __builtin_amdgcn_mfma_f32_16x16x32_bf16(af[r], bfr[c], acc[r][c], 0, 0, 0);
    __syncthreads();
  }
#pragma unroll
  for (int r = 0; r < 4; ++r) {
    int mrow = m0 + wr * 64 + r * 16 + lg * 4;
#pragma unroll
    for (int c = 0; c < 4; ++c) {
      int col = n0 + wc * 64 + c * 16 + l15;
      float bv = bias[col];
#pragma unroll
      for (int j = 0; j < 4; ++j) {
        float v = acc[r][c][j] + bv;
        if (OUT_F32)
          ((float*)Cout)[(size_t)(mrow + j) * N + col] = v;
        else
          ((u16*)Cout)[(size_t)(mrow + j) * N + col] = f2bf(v);
      }
    }
  }
}

// ---------------- RoPE + scatter qkv -> q_all / k / v ----------------
// q additionally scaled by HD^-0.5 * log2(e) (scores consumed in exp2 domain).
__global__ void rope_scatter(const u16* __restrict__ qkv, const float* __restrict__ freqs,
                             u16* __restrict__ qo, u16* __restrict__ ko, u16* __restrict__ vo) {
  const int per_row = QKVN / 8;  // 320
  const int total = B_ * S_ * per_row;
  int i = blockIdx.x * blockDim.x + threadIdx.x;
  int stride = gridDim.x * blockDim.x;
  for (; i < total; i += stride) {
    int m = i / per_row;
    int n8 = (i - m * per_row) * 8;
    int b = m >> 11, s = m & 2047;
    uint4 raw = *(const uint4*)(qkv + (size_t)m * QKVN + n8);
    const u16* u = (const u16*)&raw;
    if (n8 < 2304) {
      int d = (n8 < 2048) ? (n8 & 255) : (n8 - 2048);
      float scl = (n8 < 2048) ? (0.0625f * 1.44269504f) : 1.0f;
      const float* fp = freqs + ((size_t)s * 128 + (d >> 1)) * 2;
      float4 f0 = *(const float4*)fp;
      float4 f1 = *(const float4*)(fp + 4);
      float fc[8] = {f0.x, f0.y, f0.z, f0.w, f1.x, f1.y, f1.z, f1.w};
      u16 o[8];
#pragma unroll
      for (int p = 0; p < 4; ++p) {
        float r = bf2f(u[2 * p]), im = bf2f(u[2 * p + 1]);
        float c = fc[2 * p], sn = fc[2 * p + 1];
        o[2 * p] = f2bf((r * c - im * sn) * scl);
        o[2 * p + 1] = f2bf((r * sn + im * c) * scl);
      }
      u16* dst;
      if (n8 < 2048) {
        int h = n8 >> 8;
        dst = qo + (((size_t)(b * NH_ + h) * S_ + s) << 8) + (n8 & 255);
      } else {
        dst = ko + (((size_t)(b * S_ + s)) << 8) + d;
      }
      *(uint4*)dst = *(const uint4*)o;
    } else {
      int d = n8 - 2304;
      u16* dst = vo + (((size_t)(b * S_ + s)) << 8) + d;
      *(uint4*)dst = raw;
    }
  }
}

// ---------------- flash attention (causal), swapped-QK^T in-lane softmax ----------------
// 4 waves x 16 q-rows (QBLK=64), KBLK=64. Each lane owns ONE q (= lane&15):
// QK^T computed as mfma(K,Q) -> S^T[k][q], softmax reduction is in-register
// (15 fmax / 15 add + 2 shfl), PV computed swapped -> O^T (col=q) so m/l/rescale
// stay lane-local. P^T re-fragments via per-wave 2KB LDS tile (wave-synchronous).
__global__ __launch_bounds__(256) void flash_attn(const u16* __restrict__ Q, const u16* __restrict__ Kg,
                                                  const u16* __restrict__ VT, u16* __restrict__ O) {
  __shared__ u16 Ks[64 * 256];    // 32 KB, rows 512B, XOR-swizzled
  __shared__ u16 Vs[256 * 64];    // 32 KB (V^T), rows 128B, XOR-swizzled
  __shared__ u16 Ps[4 * 16 * 64]; // 8 KB, per-wave P tiles [16 q][64 k], swizzled
  int qt = 31 - ((int)blockIdx.x & 31);
  int bh = (int)blockIdx.x >> 5;
  int b = bh >> 3, h = bh & 7;
  int tid = threadIdx.x, w = tid >> 6, lane = tid & 63;
  int l15 = lane & 15, lg = lane >> 4;
  int q0 = qt << 6;
  int qrow = q0 + w * 16 + l15;  // this lane's q row

  bf16x8 qf[8];
  const u16* qb = Q + ((size_t)bh * S_ + qrow) * HD_ + lg * 8;
#pragma unroll
  for (int kc = 0; kc < 8; ++kc) qf[kc] = *(const bf16x8*)(qb + kc * 32);

  float m_r = -3.0e38f, l_r = 0.f;
  f32x4 oaccT[16] = {};  // [dt][j]: d = dt*16 + lg*4 + j, q = l15
  const char* KsB = (const char*)Ks;
  const char* VsB = (const char*)Vs;
  char* psb = (char*)Ps + w * 2048;
  int swzq = (l15 & 7) << 4;

  for (int kt = 0; kt <= qt; ++kt) {
    __syncthreads();
    {  // stage K tile [64][256]
      const u16* kgb = Kg + ((size_t)(b * S_ + kt * 64)) * HD_;
#pragma unroll
      for (int p = 0; p < 8; ++p) {
        int idx = p * 256 + tid;
        int row = idx >> 5, c16 = idx & 31;
        uint4 val = *(const uint4*)(kgb + row * HD_ + c16 * 8);
        *(uint4*)((char*)Ks + row * 512 + ((c16 * 16) ^ ((row & 7) << 4))) = val;
      }
      // stage V^T tile [256][64]
      const u16* vgb = VT + ((size_t)b * HD_) * S_ + kt * 64;
#pragma unroll
      for (int p = 0; p < 8; ++p) {
        int idx = p * 256 + tid;
        int d = idx >> 3, c16 = idx & 7;
        uint4 val = *(const uint4*)(vgb + (size_t)d * S_ + c16 * 8);
        *(uint4*)((char*)Vs + d * 128 + ((c16 * 16) ^ ((d & 7) << 4))) = val;
      }
    }
    __syncthreads();

    // QK^T swapped: sc[ct][j] = S^T[k = kt*64 + ct*16 + lg*4 + j][q = l15]
    f32x4 sc[4] = {};
    __builtin_amdgcn_s_setprio(1);
#pragma unroll
    for (int kc = 0; kc < 8; ++kc) {
#pragma unroll
      for (int ct = 0; ct < 4; ++ct) {
        int row = ct * 16 + l15;
        bf16x8 kf = *(const bf16x8*)(KsB + row * 512 + ((kc * 64 + lg * 16) ^ ((row & 7) << 4)));
        sc[ct] = __builtin_amdgcn_mfma_f32_16x16x32_bf16(kf, qf[kc], sc[ct], 0, 0, 0);
      }
    }
    __builtin_amdgcn_s_setprio(0);

    // in-lane online softmax (scores are in log2 domain)
    bool diag = (kt == qt);
    float tmax = -3.0e38f;
#pragma unroll
    for (int ct = 0; ct < 4; ++ct) {
#pragma unroll
      for (int j = 0; j < 4; ++j) {
        float v = sc[ct][j];
        if (diag && (kt * 64 + ct * 16 + lg * 4 + j > qrow)) v = -3.0e38f;
        sc[ct][j] = v;
        tmax = fmaxf(tmax, v);
      }
    }
    tmax = fmaxf(tmax, __shfl_xor(tmax, 16));
    tmax = fmaxf(tmax, __shfl_xor(tmax, 32));

    if (!__all(tmax - m_r <= 8.0f)) {  // defer-max (T13)
      float mnew = fmaxf(m_r, tmax);
      float scale = exp2f(m_r - mnew);
      l_r *= scale;
#pragma unroll
      for (int dt = 0; dt < 16; ++dt) oaccT[dt] *= scale;
      m_r = mnew;
    }

    float tsum = 0.f;
#pragma unroll
    for (int ct = 0; ct < 4; ++ct) {
      u16 pb[4];
#pragma unroll
      for (int j = 0; j < 4; ++j) {
        float pv = exp2f(sc[ct][j] - m_r);
        tsum += pv;
        pb[j] = f2bf(pv);
      }
      // write P[q=l15][k=ct*16+lg*4 .. +3] (8B, swizzled)
      *(unsigned long long*)(psb + l15 * 128 + ((ct * 32 + lg * 8) ^ swzq)) =
          *(const unsigned long long*)pb;
    }
    tsum += __shfl_xor(tsum, 16);
    tsum += __shfl_xor(tsum, 32);
    l_r += tsum;

    // PV swapped: oaccT[dt] += V^T-frag x P^T-frag
    __builtin_amdgcn_s_setprio(1);
#pragma unroll
    for (int s = 0; s < 2; ++s) {
      bf16x8 pf = *(const bf16x8*)(psb + l15 * 128 + ((s * 64 + lg * 16) ^ swzq));
#pragma unroll
      for (int dt = 0; dt < 16; ++dt) {
        int vrow = dt * 16 + l15;
        bf16x8 vf = *(const bf16x8*)(VsB + vrow * 128 + ((s * 64 + lg * 16) ^ ((vrow & 7) << 4)));
        oaccT[dt] = __builtin_amdgcn_mfma_f32_16x16x32_bf16(vf, pf, oaccT[dt], 0, 0, 0);
      }
    }
    __builtin_amdgcn_s_setprio(0);
  }

  // epilogue: divide by l (lane-local), write O row q = qrow
  float inv = 1.0f / l_r;
  u16* ob = O + ((size_t)(b * S_ + qrow)) * HID_ + h * HD_ + lg * 4;
#pragma unroll
  for (int dt = 0; dt < 16; ++dt) {
    u16 o4[4];
#pragma unroll
    for (int j = 0; j < 4; ++j) o4[j] = f2bf(oaccT[dt][j] * inv);
    *(unsigned long long*)(ob + dt * 16) = *(const unsigned long long*)o4;
  }
}

extern "C" void kernel_launch(void* const* d_in, const int* in_sizes, int n_in,
                              void* d_out, int out_size, void* d_ws, size_t ws_size,
                              hipStream_t stream) {
  const float* x = (const float*)d_in[0];
  const float* w_qkv = (const float*)d_in[1];
  const float* b_qkv = (const float*)d_in[2];
  const float* w_o = (const float*)d_in[3];
  const float* b_o = (const float*)d_in[4];
  const float* freqs = (const float*)d_in[5];
  // d_in[6] is the causal mask; causality is implemented directly.

  char* ws = (char*)d_ws;
  u16* xb    = (u16*)ws;                          // 33,554,432 B
  u16* wqkvT = (u16*)(ws + 33554432);             // 10,485,760 B
  u16* woT   = (u16*)(ws + 44040192);             //  8,388,608 B
  u16* qkv   = (u16*)(ws + 52428800);             // 41,943,040 B
  u16* qall  = (u16*)(ws + 94371840);             // 33,554,432 B
  u16* kbuf  = (u16*)(ws + 127926272);            //  4,194,304 B
  u16* vbuf  = (u16*)(ws + 132120576);            //  4,194,304 B
  u16* vT    = xb;    // alias: xb dead after QKV GEMM
  u16* attout = qkv;  // alias: qkv dead after rope_scatter

  cast_f32_bf16<<<2048, 256, 0, stream>>>(x, xb, (B_ * S_ * HID_) / 8);
  transpose_cast<<<dim3(QKVN / 32, HID_ / 32), dim3(32, 8), 0, stream>>>(w_qkv, wqkvT, HID_, QKVN);
  transpose_cast<<<dim3(HID_ / 32, HID_ / 32), dim3(32, 8), 0, stream>>>(w_o, woT, HID_, HID_);
  gemm_bt<false><<<dim3(64 * 20), 256, 0, stream>>>(xb, wqkvT, b_qkv, qkv, B_ * S_, QKVN, HID_);
  rope_scatter<<<2048, 256, 0, stream>>>(qkv, freqs, qall, kbuf, vbuf);
  transpose_bf16<<<dim3(HD_ / 32, S_ / 32, B_), dim3(32, 8), 0, stream>>>(vbuf, vT, S_, HD_);
  flash_attn<<<1024, 256, 0, stream>>>(qall, kbuf, vT, attout);
  gemm_bt<true><<<dim3(64 * 16), 256, 0, stream>>>(attout, woT, b_o, d_out, B_ * S_, HID_, HID_);
}

// Round 4
// 471.140 us; speedup vs baseline: 1.3546x; 1.3046x over previous
//
#include <hip/hip_runtime.h>
#include <hip/hip_bf16.h>

#define B_ 4
#define S_ 2048
#define HID_ 2048
#define NH_ 8
#define HD_ 256
#define QKVN 2560

typedef unsigned short u16;
typedef __attribute__((ext_vector_type(4))) float f32x4;
typedef __attribute__((ext_vector_type(16))) float f32x16;
typedef __attribute__((ext_vector_type(8))) short bf16x8;

__device__ __forceinline__ float bf2f(u16 u) {
  union { unsigned int i; float f; } v; v.i = ((unsigned int)u) << 16; return v.f;
}
__device__ __forceinline__ u16 f2bf(float f) {
  union { unsigned int i; float f; } v; v.f = f;
  unsigned int r = v.i + 0x7fffu + ((v.i >> 16) & 1u);
  return (u16)(r >> 16);
}

// ---------------- cast x (f32 -> bf16), 8 elems/thread ----------------
__global__ void cast_f32_bf16(const float* __restrict__ in, u16* __restrict__ out, int n8) {
  int i = blockIdx.x * blockDim.x + threadIdx.x;
  int stride = gridDim.x * blockDim.x;
  for (; i < n8; i += stride) {
    const float4* p = (const float4*)(in + (size_t)i * 8);
    float4 a = p[0], b = p[1];
    u16 o[8] = {f2bf(a.x), f2bf(a.y), f2bf(a.z), f2bf(a.w),
                f2bf(b.x), f2bf(b.y), f2bf(b.z), f2bf(b.w)};
    *(uint4*)(out + (size_t)i * 8) = *(const uint4*)o;
  }
}

// ------------- transpose + cast: in[R][C] f32 -> out[C][R] bf16 -------------
__global__ void transpose_cast(const float* __restrict__ in, u16* __restrict__ out, int R, int C) {
  __shared__ float t[32][33];
  int c0 = blockIdx.x * 32, r0 = blockIdx.y * 32;
  int tx = threadIdx.x, ty = threadIdx.y;
#pragma unroll
  for (int i = 0; i < 4; ++i)
    t[ty + i * 8][tx] = in[(size_t)(r0 + ty + i * 8) * C + c0 + tx];
  __syncthreads();
#pragma unroll
  for (int i = 0; i < 4; ++i)
    out[(size_t)(c0 + ty + i * 8) * R + r0 + tx] = f2bf(t[tx][ty + i * 8]);
}

// ------------- transpose bf16 (per-batch): in[R][C] -> out[C][R] -------------
__global__ void transpose_bf16(const u16* __restrict__ in, u16* __restrict__ out, int R, int C) {
  __shared__ u16 t[32][33];
  in += (size_t)blockIdx.z * R * C;
  out += (size_t)blockIdx.z * R * C;
  int c0 = blockIdx.x * 32, r0 = blockIdx.y * 32;
  int tx = threadIdx.x, ty = threadIdx.y;
#pragma unroll
  for (int i = 0; i < 4; ++i)
    t[ty + i * 8][tx] = in[(size_t)(r0 + ty + i * 8) * C + c0 + tx];
  __syncthreads();
#pragma unroll
  for (int i = 0; i < 4; ++i)
    out[(size_t)(c0 + ty + i * 8) * R + r0 + tx] = t[tx][ty + i * 8];
}

// ---------------- m97-style bf16 GEMM: C[M][N] = A[M][K] * BT[N][K]^T + bias ----------------
template <bool OUT_F32>
__global__ __launch_bounds__(256) void gemm_bt(const u16* __restrict__ A, const u16* __restrict__ BT,
                                               const float* __restrict__ bias, void* __restrict__ Cout,
                                               int M, int N, int K) {
  __shared__ u16 As[128 * 32];
  __shared__ u16 Bs[128 * 32];
  int nwg = gridDim.x;
  int bid = (int)blockIdx.x;
  bid = (bid & 7) * (nwg >> 3) + (bid >> 3);  // XCD swizzle (nwg % 8 == 0)
  int ntiles = N >> 7;
  int m0 = (bid / ntiles) << 7, n0 = (bid % ntiles) << 7;
  int tid = threadIdx.x, w = tid >> 6, lane = tid & 63;
  int wr = w >> 1, wc = w & 1;
  int l15 = lane & 15, lg = lane >> 4;
  f32x4 acc[4][4] = {};
  int crow = lane >> 2;
  int ccol = (lane & 3) * 8;
  for (int k0 = 0; k0 < K; k0 += 32) {
#pragma unroll
    for (int i = 0; i < 2; ++i) {
      int c = w * 2 + i;
      const u16* ga = A + (size_t)(m0 + c * 16 + crow) * K + k0 + ccol;
      const u16* gb = BT + (size_t)(n0 + c * 16 + crow) * K + k0 + ccol;
      __builtin_amdgcn_global_load_lds((const __attribute__((address_space(1))) void*)ga,
                                       (__attribute__((address_space(3))) void*)(As + c * 512), 16, 0, 0);
      __builtin_amdgcn_global_load_lds((const __attribute__((address_space(1))) void*)gb,
                                       (__attribute__((address_space(3))) void*)(Bs + c * 512), 16, 0, 0);
    }
    __syncthreads();
    bf16x8 af[4], bfr[4];
#pragma unroll
    for (int r = 0; r < 4; ++r)
      af[r] = *(const bf16x8*)&As[(wr * 64 + r * 16 + l15) * 32 + lg * 8];
#pragma unroll
    for (int c = 0; c < 4; ++c)
      bfr[c] = *(const bf16x8*)&Bs[(wc * 64 + c * 16 + l15) * 32 + lg * 8];
#pragma unroll
    for (int r = 0; r < 4; ++r)
#pragma unroll
      for (int c = 0; c < 4; ++c)
        acc[r][c] = __builtin_amdgcn_mfma_f32_16x16x32_bf16(af[r], bfr[c], acc[r][c], 0, 0, 0);
    __syncthreads();
  }
#pragma unroll
  for (int r = 0; r < 4; ++r) {
    int mrow = m0 + wr * 64 + r * 16 + lg * 4;
#pragma unroll
    for (int c = 0; c < 4; ++c) {
      int col = n0 + wc * 64 + c * 16 + l15;
      float bv = bias[col];
#pragma unroll
      for (int j = 0; j < 4; ++j) {
        float v = acc[r][c][j] + bv;
        if (OUT_F32)
          ((float*)Cout)[(size_t)(mrow + j) * N + col] = v;
        else
          ((u16*)Cout)[(size_t)(mrow + j) * N + col] = f2bf(v);
      }
    }
  }
}

// ---------------- RoPE + scatter qkv -> q_pack [b][s][h][d] / k / v ----------------
// q scaled by HD^-0.5 * log2(e) (scores consumed in exp2 domain).
__global__ void rope_scatter(const u16* __restrict__ qkv, const float* __restrict__ freqs,
                             u16* __restrict__ qo, u16* __restrict__ ko, u16* __restrict__ vo) {
  const int per_row = QKVN / 8;  // 320
  const int total = B_ * S_ * per_row;
  int i = blockIdx.x * blockDim.x + threadIdx.x;
  int stride = gridDim.x * blockDim.x;
  for (; i < total; i += stride) {
    int m = i / per_row;
    int n8 = (i - m * per_row) * 8;
    int b = m >> 11, s = m & 2047;
    uint4 raw = *(const uint4*)(qkv + (size_t)m * QKVN + n8);
    const u16* u = (const u16*)&raw;
    if (n8 < 2304) {
      int d = (n8 < 2048) ? (n8 & 255) : (n8 - 2048);
      float scl = (n8 < 2048) ? (0.0625f * 1.44269504f) : 1.0f;
      const float* fp = freqs + ((size_t)s * 128 + (d >> 1)) * 2;
      float4 f0 = *(const float4*)fp;
      float4 f1 = *(const float4*)(fp + 4);
      float fc[8] = {f0.x, f0.y, f0.z, f0.w, f1.x, f1.y, f1.z, f1.w};
      u16 o[8];
#pragma unroll
      for (int p = 0; p < 4; ++p) {
        float r = bf2f(u[2 * p]), im = bf2f(u[2 * p + 1]);
        float c = fc[2 * p], sn = fc[2 * p + 1];
        o[2 * p] = f2bf((r * c - im * sn) * scl);
        o[2 * p + 1] = f2bf((r * sn + im * c) * scl);
      }
      u16* dst;
      if (n8 < 2048) {
        dst = qo + (size_t)m * 2048 + n8;  // packed [b][s][h][d]
      } else {
        dst = ko + (((size_t)(b * S_ + s)) << 8) + d;
      }
      *(uint4*)dst = *(const uint4*)o;
    } else {
      int d = n8 - 2304;
      u16* dst = vo + (((size_t)(b * S_ + s)) << 8) + d;
      *(uint4*)dst = raw;
    }
  }
}

// ---------------- flash attention, GQA head-packed, 32x32 MFMA ----------------
// Q rows = s*8+h packed: QBLK=256 rows (32 s x 8 heads) per block, 8 waves x 32 q-cols.
// KBLK=64, K/V double-buffered LDS (128KB), global_load_lds with pre-swizzled source.
// Swapped QK^T (mfma(K,Q)) -> lane owns q=lane&31; in-register P via permlane32_swap.

#define STAGE_K(bufofs, kt)                                                                       \
  do {                                                                                            \
    const u16* _src = Kp + ((size_t)(b * S_ + (kt) * 64)) * HD_;                                  \
    _Pragma("unroll") for (int _p = 0; _p < 4; ++_p) {                                            \
      int _idx = _p * 512 + tid;                                                                  \
      int _row = _idx >> 5, _c = _idx & 31;                                                       \
      int _scol = (((_c * 16) ^ ((_row & 7) << 4)) >> 1);                                         \
      __builtin_amdgcn_global_load_lds(                                                           \
          (const __attribute__((address_space(1))) void*)(_src + (size_t)_row * HD_ + _scol),     \
          (__attribute__((address_space(3))) void*)(KsBase + (bufofs) + _idx * 8), 16, 0, 0);     \
    }                                                                                             \
  } while (0)

#define STAGE_V(bufofs, kt)                                                                       \
  do {                                                                                            \
    const u16* _src = VTp + (size_t)b * HD_ * S_ + (kt) * 64;                                     \
    _Pragma("unroll") for (int _p = 0; _p < 4; ++_p) {                                            \
      int _idx = _p * 512 + tid;                                                                  \
      int _d = _idx >> 3, _c = _idx & 7;                                                          \
      int _scol = (((_c * 16) ^ ((_d & 7) << 4)) >> 1);                                           \
      __builtin_amdgcn_global_load_lds(                                                           \
          (const __attribute__((address_space(1))) void*)(_src + (size_t)_d * S_ + _scol),        \
          (__attribute__((address_space(3))) void*)(VsBase + (bufofs) + _idx * 8), 16, 0, 0);     \
    }                                                                                             \
  } while (0)

__global__ __launch_bounds__(512, 2) void flash_attn(const u16* __restrict__ Qp, const u16* __restrict__ Kp,
                                                     const u16* __restrict__ VTp, u16* __restrict__ Op) {
  __shared__ u16 Ks[2][64 * 256];   // 64 KB
  __shared__ u16 Vs[2][256 * 64];   // 64 KB
  int bid = (int)blockIdx.x;
  int b = bid & 3, t = bid >> 2;    // t = s-tile (32 s-positions)
  int tid = threadIdx.x;
  int w = tid >> 6, l = tid & 63;
  int l31 = l & 31, lh = l >> 5;
  int q_local = w * 32 + l31;
  size_t qrow = (size_t)b * 16384 + (size_t)t * 256 + q_local;
  int s_g = t * 32 + (q_local >> 3);  // this lane's s position

  u16* KsBase = &Ks[0][0];
  u16* VsBase = &Vs[0][0];

  // Q B-fragments: 16 hd-steps of 16, lane holds Q[q=l31][hd = step*16 + lh*8 + e]
  bf16x8 qf[16];
  const u16* qp = Qp + qrow * HD_ + lh * 8;
#pragma unroll
  for (int s = 0; s < 16; ++s) qf[s] = *(const bf16x8*)(qp + s * 16);

  f32x16 oacc[8] = {};  // O^T: d = dt*32 + (j&3)+8*(j>>2)+4*lh, q = l31
  float m_r = -3.0e38f, l_r = 0.f;
  int nkv = t / 2 + 1;

  STAGE_K(0, 0);
  STAGE_V(0, 0);
  __syncthreads();
  int cur = 0;
  for (int kt = 0; kt < nkv; ++kt) {
    if (kt + 1 < nkv) {
      STAGE_K((cur ^ 1) * 16384, kt + 1);
      STAGE_V((cur ^ 1) * 16384, kt + 1);
    }
    const char* Kb = (const char*)KsBase + cur * 32768;
    const char* Vb = (const char*)VsBase + cur * 32768;
#pragma unroll
    for (int tau = 0; tau < 2; ++tau) {
      int k0 = kt * 64 + tau * 32;
      if (k0 > t * 32 + 31) break;  // fully-masked half-tile (block-uniform)
      // QK^T swapped: scv[j] = S^T[k_rel=(j&3)+8*(j>>2)+4*lh][q=l31]
      f32x16 scv = {};
      __builtin_amdgcn_s_setprio(1);
#pragma unroll
      for (int s = 0; s < 16; ++s) {
        int row = tau * 32 + l31;
        bf16x8 kf = *(const bf16x8*)(Kb + row * 512 + ((s * 32 + lh * 16) ^ ((row & 7) << 4)));
        scv = __builtin_amdgcn_mfma_f32_32x32x16_bf16(kf, qf[s], scv, 0, 0, 0);
      }
      __builtin_amdgcn_s_setprio(0);
      if (k0 + 31 > t * 32) {  // causal mask needed on this half-tile
#pragma unroll
        for (int j = 0; j < 16; ++j) {
          int kg = k0 + (j & 3) + 8 * (j >> 2) + 4 * lh;
          if (kg > s_g) scv[j] = -3.0e38f;
        }
      }
      float tmax = -3.0e38f;
#pragma unroll
      for (int j = 0; j < 16; ++j) tmax = fmaxf(tmax, scv[j]);
      tmax = fmaxf(tmax, __shfl_xor(tmax, 32));
      if (!__all(tmax - m_r <= 8.0f)) {  // defer-max (T13)
        float mnew = fmaxf(m_r, tmax);
        float sc = exp2f(m_r - mnew);
        l_r *= sc;
#pragma unroll
        for (int dt = 0; dt < 8; ++dt) oacc[dt] *= sc;
        m_r = mnew;
      }
      float ts = 0.f;
      unsigned cpk[8];
#pragma unroll
      for (int mi = 0; mi < 8; ++mi) {
        float p0 = exp2f(scv[2 * mi] - m_r);
        float p1 = exp2f(scv[2 * mi + 1] - m_r);
        ts += p0 + p1;
        cpk[mi] = ((unsigned)f2bf(p1) << 16) | f2bf(p0);
      }
      ts += __shfl_xor(ts, 32);
      l_r += ts;
      // in-register P^T -> B-fragments via cross-half swap (T12).
      // v_permlane32_swap_b32 A,B: A' = [A.lo, B.lo], B' = [A.hi, B.hi].
      // swap(cpk0,cpk2): cpk0' = w0 of pa, cpk2' = w2 of pa; etc.
      asm volatile("v_permlane32_swap_b32 %0, %1" : "+v"(cpk[0]), "+v"(cpk[2]));
      asm volatile("v_permlane32_swap_b32 %0, %1" : "+v"(cpk[1]), "+v"(cpk[3]));
      asm volatile("v_permlane32_swap_b32 %0, %1" : "+v"(cpk[4]), "+v"(cpk[6]));
      asm volatile("v_permlane32_swap_b32 %0, %1" : "+v"(cpk[5]), "+v"(cpk[7]));
      union { unsigned u[4]; bf16x8 v; } pa, pb;
      pa.u[0] = cpk[0]; pa.u[1] = cpk[1]; pa.u[2] = cpk[2]; pa.u[3] = cpk[3];
      pb.u[0] = cpk[4]; pb.u[1] = cpk[5]; pb.u[2] = cpk[6]; pb.u[3] = cpk[7];
      // PV swapped: O^T += V^T-frag x P-frag, k-steps 2*tau, 2*tau+1
      __builtin_amdgcn_s_setprio(1);
#pragma unroll
      for (int dt = 0; dt < 8; ++dt) {
        int d = dt * 32 + l31;
        int swz = (d & 7) << 4;
        bf16x8 va = *(const bf16x8*)(Vb + d * 128 + (((2 * tau) * 32 + lh * 16) ^ swz));
        oacc[dt] = __builtin_amdgcn_mfma_f32_32x32x16_bf16(va, pa.v, oacc[dt], 0, 0, 0);
        bf16x8 vb2 = *(const bf16x8*)(Vb + d * 128 + (((2 * tau + 1) * 32 + lh * 16) ^ swz));
        oacc[dt] = __builtin_amdgcn_mfma_f32_32x32x16_bf16(vb2, pb.v, oacc[dt], 0, 0, 0);
      }
      __builtin_amdgcn_s_setprio(0);
    }
    __syncthreads();
    cur ^= 1;
  }

  // epilogue: O[qrow][d] = oacc / l  (qrow*256+d == [b*s][h*256+d] flat)
  float inv = 1.0f / l_r;
  u16* ob = Op + qrow * 256;
#pragma unroll
  for (int dt = 0; dt < 8; ++dt) {
#pragma unroll
    for (int jj = 0; jj < 4; ++jj) {
      int d0 = dt * 32 + jj * 8 + 4 * lh;
      u16 o4[4];
#pragma unroll
      for (int e = 0; e < 4; ++e) o4[e] = f2bf(oacc[dt][jj * 4 + e] * inv);
      *(unsigned long long*)(ob + d0) = *(const unsigned long long*)o4;
    }
  }
}

extern "C" void kernel_launch(void* const* d_in, const int* in_sizes, int n_in,
                              void* d_out, int out_size, void* d_ws, size_t ws_size,
                              hipStream_t stream) {
  const float* x = (const float*)d_in[0];
  const float* w_qkv = (const float*)d_in[1];
  const float* b_qkv = (const float*)d_in[2];
  const float* w_o = (const float*)d_in[3];
  const float* b_o = (const float*)d_in[4];
  const float* freqs = (const float*)d_in[5];
  // d_in[6] is the causal mask; causality is implemented directly.

  char* ws = (char*)d_ws;
  u16* xb    = (u16*)ws;                          // 33,554,432 B
  u16* wqkvT = (u16*)(ws + 33554432);             // 10,485,760 B
  u16* woT   = (u16*)(ws + 44040192);             //  8,388,608 B
  u16* qkv   = (u16*)(ws + 52428800);             // 41,943,040 B
  u16* qall  = (u16*)(ws + 94371840);             // 33,554,432 B
  u16* kbuf  = (u16*)(ws + 127926272);            //  4,194,304 B
  u16* vbuf  = (u16*)(ws + 132120576);            //  4,194,304 B
  u16* vT    = xb;    // alias: xb dead after QKV GEMM
  u16* attout = qkv;  // alias: qkv dead after rope_scatter

  cast_f32_bf16<<<2048, 256, 0, stream>>>(x, xb, (B_ * S_ * HID_) / 8);
  transpose_cast<<<dim3(QKVN / 32, HID_ / 32), dim3(32, 8), 0, stream>>>(w_qkv, wqkvT, HID_, QKVN);
  transpose_cast<<<dim3(HID_ / 32, HID_ / 32), dim3(32, 8), 0, stream>>>(w_o, woT, HID_, HID_);
  gemm_bt<false><<<dim3(64 * 20), 256, 0, stream>>>(xb, wqkvT, b_qkv, qkv, B_ * S_, QKVN, HID_);
  rope_scatter<<<2048, 256, 0, stream>>>(qkv, freqs, qall, kbuf, vbuf);
  transpose_bf16<<<dim3(HD_ / 32, S_ / 32, B_), dim3(32, 8), 0, stream>>>(vbuf, vT, S_, HD_);
  flash_attn<<<256, 512, 0, stream>>>(qall, kbuf, vT, attout);
  gemm_bt<true><<<dim3(64 * 16), 256, 0, stream>>>(attout, woT, b_o, d_out, B_ * S_, HID_, HID_);
}